// Round 9
// baseline (322.964 us; speedup 1.0000x reference)
//
#include <hip/hip_runtime.h>

// Problem constants (B=8, H=4096, C=512, GROUPS=4)
constexpr int D         = 128;        // d = C/GROUPS
constexpr int NE        = 512;        // n_embed
constexpr int NROWS     = 131072;     // B*H*GROUPS
constexpr int CC        = 512;        // C
constexpr int OUT_ELEMS = 16777216;   // MROWS*CC

// ws layout (bytes):
//   [0]                 : float diff accumulator
//   [1024, +2048)       : entab - ||e_j||^2 fp32, 512 floats
//   [4096, +262144)     : esw - 16 chunks x 16384 B:
//        [0,8192)   Eh : fp16(-2E), MFMA A-frag layout
//        [8192,16384) El: fp16((-2E - Eh)*2048)
//   [266240, +4194304)  : P[4][512][512] fp32

using half8  = __attribute__((ext_vector_type(8))) _Float16;
using f32x16 = __attribute__((ext_vector_type(16))) float;
using f32x4  = __attribute__((ext_vector_type(4))) float;

// fp16 min normal: leading term below this is zeroed so the (possibly
// flushed-by-MFMA) denormal carries nothing; residual then holds it all.
#define F16_MINNORM 6.103515625e-05f

// plain 2-term f16 split of 8 floats: v = t1 + t2/2048 (+ ~2^-21 rel)
__device__ __forceinline__ void split8v(f32x4 a, f32x4 b,
                                        half8& t1, half8& t2) {
    float v[8] = {a[0], a[1], a[2], a[3], b[0], b[1], b[2], b[3]};
#pragma unroll
    for (int i = 0; i < 8; i++) {
        float vc = (__builtin_fabsf(v[i]) < F16_MINNORM) ? 0.0f : v[i];
        _Float16 h = (_Float16)vc;
        float r = v[i] - (float)h;
        t1[i] = h;
        t2[i] = (_Float16)(r * 2048.0f);
    }
}

// ---------------------------------------------------------------------------
// K0: eprep — fp16 split of -2E into MFMA A-frag layout + ||e||^2 table.
// The ONLY producer the argmin blocks depend on; tiny (16 blocks).
__global__ void eprep_kernel(const float* __restrict__ embed,
                             unsigned short* __restrict__ esw,
                             float* __restrict__ entab,
                             float* __restrict__ ws_diff) {
    const int chunk = blockIdx.x;
    const int tid = threadIdx.x;
    const int cl = tid >> 3;    // code in chunk (0..31) == A-row == lane&31
    const int seg = tid & 7;    // k-group of 16 (== kk)
    const float* src = embed + (size_t)(chunk * 32 + cl) * D + seg * 16;
    unsigned short* cb = esw + (size_t)chunk * 8192;  // shorts per chunk

    float ss = 0.f;
#pragma unroll
    for (int g2 = 0; g2 < 2; g2++) {   // g2 == h5 (k-half of the MFMA slice)
        f32x4 a = ((const f32x4*)src)[g2 * 2 + 0];
        f32x4 b = ((const f32x4*)src)[g2 * 2 + 1];
        float v[8] = {a[0], a[1], a[2], a[3], b[0], b[1], b[2], b[3]};
        half8 t1, t2;
#pragma unroll
        for (int i = 0; i < 8; i++) {
            ss += v[i] * v[i];
            float m2 = -2.0f * v[i];
            float m2c = (__builtin_fabsf(m2) < F16_MINNORM) ? 0.0f : m2;
            _Float16 h = (_Float16)m2c;
            float r = m2 - (float)h;
            t1[i] = h;
            t2[i] = (_Float16)(r * 2048.0f);   // scaled residual, fp16-normal
        }
        const int idx = seg * 512 + g2 * 256 + cl * 8;
        *(half8*)(cb + idx) = t1;          // Eh
        *(half8*)(cb + 4096 + idx) = t2;   // El
    }
    ss += __shfl_down(ss, 4, 8);
    ss += __shfl_down(ss, 2, 8);
    ss += __shfl_down(ss, 1, 8);
    if (seg == 0) entab[chunk * 32 + cl] = ss;
    if (chunk == 0 && tid == 0) ws_diff[0] = 0.0f;
}

// ---------------------------------------------------------------------------
// K1: blocks [0,1024)   = argmin (MFMA distance scan, 8KB-granule pipeline)
//     blocks [1024,1088)= MFMA pgemm P[g][j][c] = sum_k E[j,k]*W[c,g*128+k]
// Granule = 32 codes x 64 k of (Eh,El) = 8 KB. 3-slot LDS ring (24 KB) +
// entab (2 KB) = 26.6 KB -> >=4 argmin blocks/CU co-resident (vs 3 at the
// old 51 KB). Stage = 2 global_load_lds per wave per granule; counted
// s_waitcnt vmcnt(2) (NEVER 0 in-loop) keeps the next granule's loads in
// flight across the barrier. acc accumulates over the 2 granules of each
// 32-code chunk, then scan. launch_bounds(256,6) pins VGPR<=85 (argmin
// path uses 84; pgemm path spills but is 64 hidden blocks).
__global__ __launch_bounds__(256, 6)
void main_kernel(const float* __restrict__ z,
                 const unsigned short* __restrict__ esw,
                 const float* __restrict__ entab,
                 const float* __restrict__ embed,
                 const float* __restrict__ projw,
                 float* __restrict__ P,
                 float* __restrict__ ws_diff,
                 float* __restrict__ ind_f) {
    __shared__ __align__(16) unsigned char ebuf[3 * 8192];   // 3-slot granule ring
    __shared__ __align__(16) float entab_s[512];
    const int tid = threadIdx.x;
    const int lane = tid & 63;
    const int wave = tid >> 6;
    const int h5 = lane >> 5, l5 = lane & 31;

    if (blockIdx.x >= 1024) {
        // ---- MFMA pgemm: wave-job = (g, cblk, quad) ----
        const int job  = (blockIdx.x - 1024) * 4 + wave;   // 0..255
        const int g    = job >> 6;                // 0..3
        const int cblk = (job >> 2) & 15;         // 0..15 (32 c's each)
        const int quad = job & 3;                 // 0..3  (4 chunks of 32 codes)

        half8 wh[8], wl[8];
        {
            const float* wr = projw + (size_t)(cblk * 32 + l5) * CC + g * D + h5 * 8;
#pragma unroll
            for (int kk = 0; kk < 8; kk++) {
                f32x4 a = *(const f32x4*)(wr + kk * 16);
                f32x4 b = *(const f32x4*)(wr + kk * 16 + 4);
                split8v(a, b, wh[kk], wl[kk]);
            }
        }
#pragma unroll 1
        for (int q = 0; q < 4; q++) {
            const int ch = quad * 4 + q;
            const float* er = embed + (size_t)(ch * 32 + l5) * D + h5 * 8;
            f32x16 accA = (f32x16)(0.0f), accB = (f32x16)(0.0f);
#pragma unroll
            for (int kk = 0; kk < 8; kk++) {
                f32x4 a = *(const f32x4*)(er + kk * 16);
                f32x4 b = *(const f32x4*)(er + kk * 16 + 4);
                half8 eh, el;
                split8v(a, b, eh, el);
                accA = __builtin_amdgcn_mfma_f32_32x32x16_f16(eh, wh[kk], accA, 0, 0, 0);
                accB = __builtin_amdgcn_mfma_f32_32x32x16_f16(eh, wl[kk], accB, 0, 0, 0);
                accB = __builtin_amdgcn_mfma_f32_32x32x16_f16(el, wh[kk], accB, 0, 0, 0);
            }
#pragma unroll
            for (int r = 0; r < 16; r++) {
                const int jl = (r & 3) + 8 * (r >> 2) + 4 * h5;
                P[(size_t)g * 262144 + (size_t)(ch * 32 + jl) * CC + cblk * 32 + l5] =
                    fmaf(accB[r], 4.8828125e-4f, accA[r]);
            }
        }
        return;
    }

    // ---- argmin body ----
    const int rb = blockIdx.x * 128 + wave * 32;

    // stage granule g (chunk g>>1, k-half g&1) into ring slot `slot`.
    // 8 KB: waves 0,1 cover the Eh half (4 KB), waves 2,3 the El half;
    // 2 x 1024 B loads per wave. LDS dst wave-uniform; HW adds lane*16.
    const int part = wave >> 1, wsub = wave & 1;
    auto stageG = [&](int g, int slot) {
        const int c = g >> 1, hf = g & 1;
        const unsigned char* s = (const unsigned char*)esw + (size_t)c * 16384 +
                                 part * 8192 + hf * 4096 + wsub * 2048 + lane * 16;
        unsigned char* d = &ebuf[slot * 8192 + part * 4096 + wsub * 2048];
#pragma unroll
        for (int it = 0; it < 2; it++)
            __builtin_amdgcn_global_load_lds(
                (const __attribute__((address_space(1))) unsigned int*)(s + it * 1024),
                (__attribute__((address_space(3))) unsigned int*)(d + it * 1024),
                16, 0, 0);
    };

    // prologue: entab->LDS, stage granules 0,1; then z load+convert (vmcnt
    // in-order: entab/g0/z all retire before the first in-loop vmcnt(2)).
    if (tid < 128)
        __builtin_amdgcn_global_load_lds(
            (const __attribute__((address_space(1))) unsigned int*)(entab + tid * 4),
            (__attribute__((address_space(3))) unsigned int*)(entab_s + tid * 4),
            16, 0, 0);
    stageG(0, 0);
    stageG(1, 1);

    // X fragments: B-frag for kk holds X[n=l5][k = kk*16 + h5*8 + j]
    half8 x1[8], x2[8];
    float xn = 0.f;
    {
        const f32x4* zr = (const f32x4*)(z + (size_t)(rb + l5) * D + h5 * 8);
#pragma unroll
        for (int kk = 0; kk < 8; kk++) {
            f32x4 a = __builtin_nontemporal_load(zr + kk * 4);
            f32x4 b = __builtin_nontemporal_load(zr + kk * 4 + 1);
            xn += a[0]*a[0] + a[1]*a[1] + a[2]*a[2] + a[3]*a[3] +
                  b[0]*b[0] + b[1]*b[1] + b[2]*b[2] + b[3]*b[3];
            split8v(a, b, x1[kk], x2[kk]);
        }
    }

    float minv = 3.0e38f;
    int   mini = 0;

    int bs = 0;   // ring slot of granule g
#pragma unroll 1
    for (int c = 0; c < 16; c++) {
        f32x16 accA = (f32x16)(0.0f), accB = (f32x16)(0.0f);
#pragma unroll
        for (int hf = 0; hf < 2; hf++) {
            const int g = c * 2 + hf;
            // granule g staged (leave granule g+1's 2 loads in flight)
            if (g < 31) { asm volatile("s_waitcnt vmcnt(2)" ::: "memory"); }
            else        { asm volatile("s_waitcnt vmcnt(0)" ::: "memory"); }
            __builtin_amdgcn_s_barrier();
            __builtin_amdgcn_sched_barrier(0);
            // slot (bs+2)%3 was last read at iteration g-1; all waves past
            if (g < 30) stageG(g + 2, bs == 0 ? 2 : bs - 1);

            const unsigned char* ldsb = &ebuf[bs * 8192];
            __builtin_amdgcn_s_setprio(1);
#pragma unroll
            for (int kk2 = 0; kk2 < 4; kk2++) {
                const int fo = kk2 * 1024 + h5 * 512 + l5 * 16;
                half8 e1 = *(const half8*)(ldsb + fo);
                half8 e2 = *(const half8*)(ldsb + 4096 + fo);
                const int kx = hf * 4 + kk2;
                accA = __builtin_amdgcn_mfma_f32_32x32x16_f16(e1, x1[kx], accA, 0, 0, 0);
                accB = __builtin_amdgcn_mfma_f32_32x32x16_f16(e1, x2[kx], accB, 0, 0, 0);
                accB = __builtin_amdgcn_mfma_f32_32x32x16_f16(e2, x1[kx], accB, 0, 0, 0);
            }
            __builtin_amdgcn_s_setprio(0);
            bs = (bs == 2) ? 0 : bs + 1;
        }

        // ||e||^2 from LDS (broadcast reads, no vmcnt traffic)
        f32x4 enr[4];
#pragma unroll
        for (int u = 0; u < 4; u++)
            enr[u] = *(const f32x4*)&entab_s[c * 32 + h5 * 4 + u * 8];

        // scan: dist = accA + 2^-11 * accB + ||e||^2 ; monotone code order
        const int cb2 = c * 32 + h5 * 4;
#pragma unroll
        for (int r = 0; r < 16; r++) {
            const float en = enr[r >> 2][r & 3];
            const int cand = cb2 + (r & 3) + 8 * (r >> 2);
            float d0 = fmaf(accB[r], 4.8828125e-4f, accA[r]) + en;
            if (d0 < minv) { minv = d0; mini = cand; }  // strict < keeps first
        }
    }

    // merge the two half-wave code sets for the same x-row (col = lane&31)
    {
        float ov = __shfl_xor(minv, 32);
        int oi = __shfl_xor(mini, 32);
        if (ov < minv || (ov == minv && oi < mini)) { minv = ov; mini = oi; }
    }
    if (lane < 32) ind_f[rb + l5] = (float)mini;

    // diff partial: ||x||^2 (both k-halves) + min proxy, lanes<32 only.
    // Fire-and-forget atomic (no return -> wave does not wait).
    float xfull = xn + __shfl_xor(xn, 32);
    float v = (lane < 32) ? (xfull + minv) : 0.0f;
#pragma unroll
    for (int off = 32; off; off >>= 1) v += __shfl_down(v, off);
    if (lane == 0) atomicAdd(ws_diff, v);
}

// ---------------------------------------------------------------------------
// K2: projection epilogue + folded finalize.
// out[m,c] = sum_g P[g][ind[m,g]][c] + b[c]. 1024 blocks x 32 out-rows
// (32768 rows total — round 8 used 512 blocks and left half of out stale).
__global__ __launch_bounds__(256)
void outproj_kernel(const float* __restrict__ P,
                    const float* __restrict__ projb,
                    const float* __restrict__ ind_f,
                    const float* __restrict__ ws_diff,
                    float* __restrict__ out,
                    float* __restrict__ diff_out) {
    __shared__ int ind_s[128];
    const int tid = threadIdx.x;
    const int mb = blockIdx.x * 32;

    if (blockIdx.x == 0 && tid == 0)
        diff_out[0] = 12.5f * ws_diff[0] * (1.0f / 16777216.0f);

    if (tid < 128) ind_s[tid] = (int)ind_f[mb * 4 + tid];
    __syncthreads();

    const int c4 = tid & 127;
    const int mh = (tid >> 7) * 16;   // 0 or 16
    const f32x4* P4  = (const f32x4*)P;
    const f32x4 bias = ((const f32x4*)projb)[c4];
    f32x4* out4 = (f32x4*)out;
#pragma unroll 4
    for (int u = 0; u < 16; u++) {
        const int ml = mh + u;
        f32x4 acc = bias;
#pragma unroll
        for (int g = 0; g < 4; g++) {
            const int ig = ind_s[ml * 4 + g];
            acc += P4[(size_t)g * 65536 + (size_t)ig * 128 + c4];
        }
        __builtin_nontemporal_store(acc, &out4[(size_t)(mb + ml) * 128 + c4]);
    }
}

// ---------------------------------------------------------------------------
extern "C" void kernel_launch(void* const* d_in, const int* in_sizes, int n_in,
                              void* d_out, int out_size, void* d_ws, size_t ws_size,
                              hipStream_t stream) {
    const float* z     = (const float*)d_in[0];
    const float* embed = (const float*)d_in[1];
    const float* projw = (const float*)d_in[2];
    const float* projb = (const float*)d_in[3];

    float* out      = (float*)d_out;
    float* diff_out = out + OUT_ELEMS;
    float* ind_f    = out + OUT_ELEMS + 1;

    char* wsb = (char*)d_ws;
    float* ws_diff = (float*)wsb;
    float* entab = (float*)(wsb + 1024);
    unsigned short* esw = (unsigned short*)(wsb + 4096);
    float* P = (float*)(wsb + 266240);

    eprep_kernel<<<16, 256, 0, stream>>>(embed, esw, entab, ws_diff);
    main_kernel<<<1088, 256, 0, stream>>>(z, esw, entab, embed, projw, P,
                                          ws_diff, ind_f);
    outproj_kernel<<<1024, 256, 0, stream>>>(P, projb, ind_f, ws_diff, out,
                                             diff_out);
}

// Round 10
// 225.247 us; speedup vs baseline: 1.4338x; 1.4338x over previous
//
#include <hip/hip_runtime.h>

// Problem constants (B=8, H=4096, C=512, GROUPS=4)
constexpr int D         = 128;        // d = C/GROUPS
constexpr int NE        = 512;        // n_embed
constexpr int NROWS     = 131072;     // B*H*GROUPS
constexpr int CC        = 512;        // C
constexpr int OUT_ELEMS = 16777216;   // MROWS*CC

// ws layout (bytes):
//   [0]                 : float diff accumulator
//   [1024, +2048)       : entab - ||e_j||^2 fp32, 512 floats
//   [4096, +262144)     : esw - 16 chunks x 16384 B:
//        [0,8192)   Eh : fp16(-2E), MFMA A-frag layout
//        [8192,16384) El: fp16((-2E - Eh)*2048)
//   [266240, +4194304)  : P[4][512][512] fp32

using half8  = __attribute__((ext_vector_type(8))) _Float16;
using f32x16 = __attribute__((ext_vector_type(16))) float;
using f32x4  = __attribute__((ext_vector_type(4))) float;

// fp16 min normal: leading term below this is zeroed so the (possibly
// flushed-by-MFMA) denormal carries nothing; residual then holds it all.
#define F16_MINNORM 6.103515625e-05f

// plain 2-term f16 split of 8 floats: v = t1 + t2/2048 (+ ~2^-21 rel)
__device__ __forceinline__ void split8v(f32x4 a, f32x4 b,
                                        half8& t1, half8& t2) {
    float v[8] = {a[0], a[1], a[2], a[3], b[0], b[1], b[2], b[3]};
#pragma unroll
    for (int i = 0; i < 8; i++) {
        float vc = (__builtin_fabsf(v[i]) < F16_MINNORM) ? 0.0f : v[i];
        _Float16 h = (_Float16)vc;
        float r = v[i] - (float)h;
        t1[i] = h;
        t2[i] = (_Float16)(r * 2048.0f);
    }
}

// ---------------------------------------------------------------------------
// K0: eprep — fp16 split of -2E into MFMA A-frag layout + ||e||^2 table.
// The ONLY producer the argmin blocks depend on; tiny (16 blocks).
__global__ void eprep_kernel(const float* __restrict__ embed,
                             unsigned short* __restrict__ esw,
                             float* __restrict__ entab,
                             float* __restrict__ ws_diff) {
    const int chunk = blockIdx.x;
    const int tid = threadIdx.x;
    const int cl = tid >> 3;    // code in chunk (0..31) == A-row == lane&31
    const int seg = tid & 7;    // k-group of 16 (== kk)
    const float* src = embed + (size_t)(chunk * 32 + cl) * D + seg * 16;
    unsigned short* cb = esw + (size_t)chunk * 8192;  // shorts per chunk

    float ss = 0.f;
#pragma unroll
    for (int g2 = 0; g2 < 2; g2++) {   // g2 == h5 (k-half of the MFMA slice)
        f32x4 a = ((const f32x4*)src)[g2 * 2 + 0];
        f32x4 b = ((const f32x4*)src)[g2 * 2 + 1];
        float v[8] = {a[0], a[1], a[2], a[3], b[0], b[1], b[2], b[3]};
        half8 t1, t2;
#pragma unroll
        for (int i = 0; i < 8; i++) {
            ss += v[i] * v[i];
            float m2 = -2.0f * v[i];
            float m2c = (__builtin_fabsf(m2) < F16_MINNORM) ? 0.0f : m2;
            _Float16 h = (_Float16)m2c;
            float r = m2 - (float)h;
            t1[i] = h;
            t2[i] = (_Float16)(r * 2048.0f);   // scaled residual, fp16-normal
        }
        const int idx = seg * 512 + g2 * 256 + cl * 8;
        *(half8*)(cb + idx) = t1;          // Eh
        *(half8*)(cb + 4096 + idx) = t2;   // El
    }
    ss += __shfl_down(ss, 4, 8);
    ss += __shfl_down(ss, 2, 8);
    ss += __shfl_down(ss, 1, 8);
    if (seg == 0) entab[chunk * 32 + cl] = ss;
    if (chunk == 0 && tid == 0) ws_diff[0] = 0.0f;
}

// ---------------------------------------------------------------------------
// K1: blocks [0,1024)   = argmin (MFMA distance scan, 8KB-granule pipeline)
//     blocks [1024,1088)= MFMA pgemm P[g][j][c] = sum_k E[j,k]*W[c,g*128+k]
// Granule = 32 codes x 64 k of (Eh,El) = 8 KB. 3-slot LDS ring (24 KB) +
// entab (2 KB) = 26.6 KB -> 6 argmin blocks/CU; with VGPR=84 (argmin path)
// that residency is reachable. launch_bounds(256,3) — NOT (256,6): the
// min-waves bound caps VGPRs KERNEL-WIDE; round 9's (256,6) forced
// VGPR_Count=40, spilling x-frags/accs to scratch (FETCH 60->490 MB).
// (256,3) reproduces round 8's allocation (argmin 84, pgemm spills - hidden).
// Counted s_waitcnt vmcnt(2) (NEVER 0 in-loop) keeps the next granule's
// loads in flight across the barrier.
__global__ __launch_bounds__(256, 3)
void main_kernel(const float* __restrict__ z,
                 const unsigned short* __restrict__ esw,
                 const float* __restrict__ entab,
                 const float* __restrict__ embed,
                 const float* __restrict__ projw,
                 float* __restrict__ P,
                 float* __restrict__ ws_diff,
                 float* __restrict__ ind_f) {
    __shared__ __align__(16) unsigned char ebuf[3 * 8192];   // 3-slot granule ring
    __shared__ __align__(16) float entab_s[512];
    const int tid = threadIdx.x;
    const int lane = tid & 63;
    const int wave = tid >> 6;
    const int h5 = lane >> 5, l5 = lane & 31;

    if (blockIdx.x >= 1024) {
        // ---- MFMA pgemm: wave-job = (g, cblk, quad) ----
        const int job  = (blockIdx.x - 1024) * 4 + wave;   // 0..255
        const int g    = job >> 6;                // 0..3
        const int cblk = (job >> 2) & 15;         // 0..15 (32 c's each)
        const int quad = job & 3;                 // 0..3  (4 chunks of 32 codes)

        half8 wh[8], wl[8];
        {
            const float* wr = projw + (size_t)(cblk * 32 + l5) * CC + g * D + h5 * 8;
#pragma unroll
            for (int kk = 0; kk < 8; kk++) {
                f32x4 a = *(const f32x4*)(wr + kk * 16);
                f32x4 b = *(const f32x4*)(wr + kk * 16 + 4);
                split8v(a, b, wh[kk], wl[kk]);
            }
        }
#pragma unroll 1
        for (int q = 0; q < 4; q++) {
            const int ch = quad * 4 + q;
            const float* er = embed + (size_t)(ch * 32 + l5) * D + h5 * 8;
            f32x16 accA = (f32x16)(0.0f), accB = (f32x16)(0.0f);
#pragma unroll
            for (int kk = 0; kk < 8; kk++) {
                f32x4 a = *(const f32x4*)(er + kk * 16);
                f32x4 b = *(const f32x4*)(er + kk * 16 + 4);
                half8 eh, el;
                split8v(a, b, eh, el);
                accA = __builtin_amdgcn_mfma_f32_32x32x16_f16(eh, wh[kk], accA, 0, 0, 0);
                accB = __builtin_amdgcn_mfma_f32_32x32x16_f16(eh, wl[kk], accB, 0, 0, 0);
                accB = __builtin_amdgcn_mfma_f32_32x32x16_f16(el, wh[kk], accB, 0, 0, 0);
            }
#pragma unroll
            for (int r = 0; r < 16; r++) {
                const int jl = (r & 3) + 8 * (r >> 2) + 4 * h5;
                P[(size_t)g * 262144 + (size_t)(ch * 32 + jl) * CC + cblk * 32 + l5] =
                    fmaf(accB[r], 4.8828125e-4f, accA[r]);
            }
        }
        return;
    }

    // ---- argmin body ----
    const int rb = blockIdx.x * 128 + wave * 32;

    // stage granule g (chunk g>>1, k-half g&1) into ring slot `slot`.
    // 8 KB: waves 0,1 cover the Eh half (4 KB), waves 2,3 the El half;
    // 2 x 1024 B loads per wave. LDS dst wave-uniform; HW adds lane*16.
    const int part = wave >> 1, wsub = wave & 1;
    auto stageG = [&](int g, int slot) {
        const int c = g >> 1, hf = g & 1;
        const unsigned char* s = (const unsigned char*)esw + (size_t)c * 16384 +
                                 part * 8192 + hf * 4096 + wsub * 2048 + lane * 16;
        unsigned char* d = &ebuf[slot * 8192 + part * 4096 + wsub * 2048];
#pragma unroll
        for (int it = 0; it < 2; it++)
            __builtin_amdgcn_global_load_lds(
                (const __attribute__((address_space(1))) unsigned int*)(s + it * 1024),
                (__attribute__((address_space(3))) unsigned int*)(d + it * 1024),
                16, 0, 0);
    };

    // prologue: entab->LDS, stage granules 0,1; then z load+convert (vmcnt
    // in-order: entab/g0/g1 retire when the z-load results are consumed).
    if (tid < 128)
        __builtin_amdgcn_global_load_lds(
            (const __attribute__((address_space(1))) unsigned int*)(entab + tid * 4),
            (__attribute__((address_space(3))) unsigned int*)(entab_s + tid * 4),
            16, 0, 0);
    stageG(0, 0);
    stageG(1, 1);

    // X fragments: B-frag for kk holds X[n=l5][k = kk*16 + h5*8 + j]
    half8 x1[8], x2[8];
    float xn = 0.f;
    {
        const f32x4* zr = (const f32x4*)(z + (size_t)(rb + l5) * D + h5 * 8);
#pragma unroll
        for (int kk = 0; kk < 8; kk++) {
            f32x4 a = __builtin_nontemporal_load(zr + kk * 4);
            f32x4 b = __builtin_nontemporal_load(zr + kk * 4 + 1);
            xn += a[0]*a[0] + a[1]*a[1] + a[2]*a[2] + a[3]*a[3] +
                  b[0]*b[0] + b[1]*b[1] + b[2]*b[2] + b[3]*b[3];
            split8v(a, b, x1[kk], x2[kk]);
        }
    }

    float minv = 3.0e38f;
    int   mini = 0;

    int bs = 0;   // ring slot of granule g
#pragma unroll 1
    for (int c = 0; c < 16; c++) {
        f32x16 accA = (f32x16)(0.0f), accB = (f32x16)(0.0f);
#pragma unroll
        for (int hf = 0; hf < 2; hf++) {
            const int g = c * 2 + hf;
            // granule g staged (leave granule g+1's 2 loads in flight)
            if (g < 31) { asm volatile("s_waitcnt vmcnt(2)" ::: "memory"); }
            else        { asm volatile("s_waitcnt vmcnt(0)" ::: "memory"); }
            __builtin_amdgcn_s_barrier();
            __builtin_amdgcn_sched_barrier(0);
            // slot (bs+2)%3 was last read at iteration g-1; all waves past
            if (g < 30) stageG(g + 2, bs == 0 ? 2 : bs - 1);

            const unsigned char* ldsb = &ebuf[bs * 8192];
            __builtin_amdgcn_s_setprio(1);
#pragma unroll
            for (int kk2 = 0; kk2 < 4; kk2++) {
                const int fo = kk2 * 1024 + h5 * 512 + l5 * 16;
                half8 e1 = *(const half8*)(ldsb + fo);
                half8 e2 = *(const half8*)(ldsb + 4096 + fo);
                const int kx = hf * 4 + kk2;
                accA = __builtin_amdgcn_mfma_f32_32x32x16_f16(e1, x1[kx], accA, 0, 0, 0);
                accB = __builtin_amdgcn_mfma_f32_32x32x16_f16(e1, x2[kx], accB, 0, 0, 0);
                accB = __builtin_amdgcn_mfma_f32_32x32x16_f16(e2, x1[kx], accB, 0, 0, 0);
            }
            __builtin_amdgcn_s_setprio(0);
            bs = (bs == 2) ? 0 : bs + 1;
        }

        // ||e||^2 from LDS (broadcast reads, no vmcnt traffic)
        f32x4 enr[4];
#pragma unroll
        for (int u = 0; u < 4; u++)
            enr[u] = *(const f32x4*)&entab_s[c * 32 + h5 * 4 + u * 8];

        // scan: dist = accA + 2^-11 * accB + ||e||^2 ; monotone code order
        const int cb2 = c * 32 + h5 * 4;
#pragma unroll
        for (int r = 0; r < 16; r++) {
            const float en = enr[r >> 2][r & 3];
            const int cand = cb2 + (r & 3) + 8 * (r >> 2);
            float d0 = fmaf(accB[r], 4.8828125e-4f, accA[r]) + en;
            if (d0 < minv) { minv = d0; mini = cand; }  // strict < keeps first
        }
    }

    // merge the two half-wave code sets for the same x-row (col = lane&31)
    {
        float ov = __shfl_xor(minv, 32);
        int oi = __shfl_xor(mini, 32);
        if (ov < minv || (ov == minv && oi < mini)) { minv = ov; mini = oi; }
    }
    if (lane < 32) ind_f[rb + l5] = (float)mini;

    // diff partial: ||x||^2 (both k-halves) + min proxy, lanes<32 only.
    // Fire-and-forget atomic (no return -> wave does not wait).
    float xfull = xn + __shfl_xor(xn, 32);
    float v = (lane < 32) ? (xfull + minv) : 0.0f;
#pragma unroll
    for (int off = 32; off; off >>= 1) v += __shfl_down(v, off);
    if (lane == 0) atomicAdd(ws_diff, v);
}

// ---------------------------------------------------------------------------
// K2: projection epilogue + folded finalize.
// out[m,c] = sum_g P[g][ind[m,g]][c] + b[c]. 1024 blocks x 32 out-rows.
__global__ __launch_bounds__(256)
void outproj_kernel(const float* __restrict__ P,
                    const float* __restrict__ projb,
                    const float* __restrict__ ind_f,
                    const float* __restrict__ ws_diff,
                    float* __restrict__ out,
                    float* __restrict__ diff_out) {
    __shared__ int ind_s[128];
    const int tid = threadIdx.x;
    const int mb = blockIdx.x * 32;

    if (blockIdx.x == 0 && tid == 0)
        diff_out[0] = 12.5f * ws_diff[0] * (1.0f / 16777216.0f);

    if (tid < 128) ind_s[tid] = (int)ind_f[mb * 4 + tid];
    __syncthreads();

    const int c4 = tid & 127;
    const int mh = (tid >> 7) * 16;   // 0 or 16
    const f32x4* P4  = (const f32x4*)P;
    const f32x4 bias = ((const f32x4*)projb)[c4];
    f32x4* out4 = (f32x4*)out;
#pragma unroll 4
    for (int u = 0; u < 16; u++) {
        const int ml = mh + u;
        f32x4 acc = bias;
#pragma unroll
        for (int g = 0; g < 4; g++) {
            const int ig = ind_s[ml * 4 + g];
            acc += P4[(size_t)g * 65536 + (size_t)ig * 128 + c4];
        }
        __builtin_nontemporal_store(acc, &out4[(size_t)(mb + ml) * 128 + c4]);
    }
}

// ---------------------------------------------------------------------------
extern "C" void kernel_launch(void* const* d_in, const int* in_sizes, int n_in,
                              void* d_out, int out_size, void* d_ws, size_t ws_size,
                              hipStream_t stream) {
    const float* z     = (const float*)d_in[0];
    const float* embed = (const float*)d_in[1];
    const float* projw = (const float*)d_in[2];
    const float* projb = (const float*)d_in[3];

    float* out      = (float*)d_out;
    float* diff_out = out + OUT_ELEMS;
    float* ind_f    = out + OUT_ELEMS + 1;

    char* wsb = (char*)d_ws;
    float* ws_diff = (float*)wsb;
    float* entab = (float*)(wsb + 1024);
    unsigned short* esw = (unsigned short*)(wsb + 4096);
    float* P = (float*)(wsb + 266240);

    eprep_kernel<<<16, 256, 0, stream>>>(embed, esw, entab, ws_diff);
    main_kernel<<<1088, 256, 0, stream>>>(z, esw, entab, embed, projw, P,
                                          ws_diff, ind_f);
    outproj_kernel<<<1024, 256, 0, stream>>>(P, projb, ind_f, ws_diff, out,
                                             diff_out);
}